// Round 3
// baseline (251.152 us; speedup 1.0000x reference)
//
#include <hip/hip_runtime.h>

#define LOG2E 1.44269504088896f

typedef _Float16 half8  __attribute__((ext_vector_type(8)));
typedef _Float16 half4v __attribute__((ext_vector_type(4)));
typedef _Float16 half2v __attribute__((ext_vector_type(2)));
typedef float    floatx4 __attribute__((ext_vector_type(4)));

__device__ __forceinline__ floatx4 mfma16(half8 a, half8 b, floatx4 c) {
    return __builtin_amdgcn_mfma_f32_16x16x32_f16(a, b, c, 0, 0, 0);
}

__device__ __forceinline__ float sigmf(float d) {
    return __builtin_amdgcn_rcpf(1.0f + __builtin_amdgcn_exp2f(d * (-LOG2E)));
}

// LDS-only barrier: s_waitcnt lgkmcnt(0) + s_barrier, leaving vmcnt in flight.
// 0xC07F = vmcnt(63) expcnt(7) lgkmcnt(0). All cross-thread data is in LDS.
#define bar_lds() do { __asm__ __volatile__("" ::: "memory"); \
    __builtin_amdgcn_s_waitcnt(0xC07F); \
    __builtin_amdgcn_s_barrier(); \
    __asm__ __volatile__("" ::: "memory"); } while (0)

// ---------------------------------------------------------------------------
// Precompute: per depth-10 subtree s (0..1023), a 16KB fp16 record in ws:
//   [0,4096)    kdiff rows: j=0..62 node (level order), row j = K0-K1 (64 h), row 63 = 0
//   [4096,8192) V^T rows:   v=0..63, col l = V[s*64+l][v]
// ---------------------------------------------------------------------------
__global__ __launch_bounds__(256, 4)
void precompute(const float* __restrict__ tkey, const float* __restrict__ tval,
                _Float16* __restrict__ rec)
{
    __shared__ _Float16 sVt[64 * 72];
    const int t = threadIdx.x;
    const int s = blockIdx.x;
    _Float16* r = rec + (size_t)s * 8192;

    // kdiff rows (63 nodes + zero row)
    {
        const int j = t >> 2, part = t & 3;
        half8 h0, h1;
        if (j < 63) {
            const int u = j + 1;
            const int f = 31 - __builtin_clz((unsigned)u);
            const int i = u - (1 << f);
            const int gidx = ((1 << (10 + f)) - 1) + (s << f) + i;
            const floatx4* kp = (const floatx4*)(tkey + (size_t)gidx * 128);
            floatx4 a0 = kp[part * 4 + 0], a1 = kp[part * 4 + 1];
            floatx4 a2 = kp[part * 4 + 2], a3 = kp[part * 4 + 3];
            floatx4 b0 = kp[16 + part * 4 + 0], b1 = kp[16 + part * 4 + 1];
            floatx4 b2 = kp[16 + part * 4 + 2], b3 = kp[16 + part * 4 + 3];
            #pragma unroll
            for (int e = 0; e < 4; ++e) {
                h0[e]     = (_Float16)(a0[e] - b0[e]);
                h0[4 + e] = (_Float16)(a1[e] - b1[e]);
                h1[e]     = (_Float16)(a2[e] - b2[e]);
                h1[4 + e] = (_Float16)(a3[e] - b3[e]);
            }
        } else {
            #pragma unroll
            for (int e = 0; e < 8; ++e) { h0[e] = (_Float16)0.f; h1[e] = (_Float16)0.f; }
        }
        *(half8*)(r + j * 64 + part * 16)     = h0;
        *(half8*)(r + j * 64 + part * 16 + 8) = h1;
    }
    // V tile -> LDS fp16
    {
        const int l = t >> 2, part = t & 3;
        const floatx4* vp = (const floatx4*)(tval + ((size_t)s * 64 + l) * 64);
        floatx4 f0 = vp[part * 4 + 0], f1 = vp[part * 4 + 1];
        floatx4 f2 = vp[part * 4 + 2], f3 = vp[part * 4 + 3];
        half8 h0, h1;
        #pragma unroll
        for (int e = 0; e < 4; ++e) {
            h0[e]     = (_Float16)f0[e];
            h0[4 + e] = (_Float16)f1[e];
            h1[e]     = (_Float16)f2[e];
            h1[4 + e] = (_Float16)f3[e];
        }
        *(half8*)(sVt + l * 72 + part * 16)     = h0;
        *(half8*)(sVt + l * 72 + part * 16 + 8) = h1;
    }
    __syncthreads();
    // V^T rows -> global
    {
        const int v = t >> 2, p2 = t & 3;
        half8 hv0, hv1;
        #pragma unroll
        for (int e = 0; e < 8; ++e) {
            hv0[e] = sVt[(16 * p2 + e) * 72 + v];
            hv1[e] = sVt[(16 * p2 + 8 + e) * 72 + v];
        }
        *(half8*)(r + 4096 + v * 64 + p2 * 16)     = hv0;
        *(half8*)(r + 4096 + v * 64 + p2 * 16 + 8) = hv1;
    }
}

// ---------------------------------------------------------------------------
// Fused tree attention. blockIdx = tb*64 + g  (same-g blocks -> same XCD L2).
// g = depth-6 leaf group (0..63), tb = batch tile of 128 rows (0..15).
// ---------------------------------------------------------------------------
__global__ __launch_bounds__(256, 3)
void tree_attn(const float* __restrict__ q,
               const float* __restrict__ tkey,
               const _Float16* __restrict__ rec,
               float* __restrict__ outp,
               int use_atomic)
{
    __shared__ floatx4 sAraw[1024];       // leaf probs [128][64] fp16, XOR-swizzled 16B chunks
    __shared__ _Float16 sProbT[128 * 72]; // node probs transposed: [b][node+1]
    __shared__ _Float16 sP0[16 * 132];    // prefix probs [sl][b] fp16

    _Float16* sA = (_Float16*)sAraw;

    const int tid  = threadIdx.x;
    const int w    = tid >> 6;
    const int lane = tid & 63;
    const int lm   = lane & 15;
    const int quad = lane >> 4;
    const int g    = blockIdx.x & 63;
    const int tb   = blockIdx.x >> 6;

    // ---- q A-fragments straight from global (fp32 -> fp16) ----
    half8 qA[2][2];
    #pragma unroll
    for (int m = 0; m < 2; ++m)
        #pragma unroll
        for (int kt = 0; kt < 2; ++kt) {
            const float* qp = q + (size_t)(tb * 128 + 32 * w + 16 * m + lm) * 64 + 32 * kt + 8 * quad;
            floatx4 f0 = *(const floatx4*)qp;
            floatx4 f1 = *(const floatx4*)(qp + 4);
            #pragma unroll
            for (int e = 0; e < 4; ++e) {
                qA[m][kt][e]     = (_Float16)f0[e];
                qA[m][kt][4 + e] = (_Float16)f1[e];
            }
        }

    // ---- prefix GEMM1: 21 path/subtree nodes (depths 0..9), B-frags on the fly ----
    {
        floatx4 acc[2][4];
        #pragma unroll
        for (int m = 0; m < 2; ++m)
            #pragma unroll
            for (int nt = 0; nt < 4; ++nt) { acc[m][nt][0]=0.f; acc[m][nt][1]=0.f; acc[m][nt][2]=0.f; acc[m][nt][3]=0.f; }
        #pragma unroll
        for (int nt = 0; nt < 4; ++nt) {
            const int j = 16 * nt + lm;
            int gidx = 0;
            const bool valid = (j < 21);
            if (j < 6) gidx = (1 << j) - 1 + (g >> (6 - j));
            else if (j < 21) {
                const int u = j - 5;
                const int e = 31 - __builtin_clz((unsigned)u);
                const int i = u - (1 << e);
                gidx = ((1 << (6 + e)) - 1) + (g << e) + i;
            }
            #pragma unroll
            for (int kt = 0; kt < 2; ++kt) {
                half8 bf;
                if (valid) {
                    const float* kb = tkey + (size_t)gidx * 128 + 32 * kt + 8 * quad;
                    floatx4 f0 = *(const floatx4*)(kb);
                    floatx4 f1 = *(const floatx4*)(kb + 4);
                    floatx4 g0 = *(const floatx4*)(kb + 64);
                    floatx4 g1 = *(const floatx4*)(kb + 68);
                    #pragma unroll
                    for (int e = 0; e < 4; ++e) {
                        bf[e]     = (_Float16)(f0[e] - g0[e]);
                        bf[4 + e] = (_Float16)(f1[e] - g1[e]);
                    }
                } else {
                    #pragma unroll
                    for (int e = 0; e < 8; ++e) bf[e] = (_Float16)0.f;
                }
                acc[0][nt] = mfma16(qA[0][kt], bf, acc[0][nt]);
                acc[1][nt] = mfma16(qA[1][kt], bf, acc[1][nt]);
            }
        }
        // sigmoid -> sProbT[b][node+1]  (D layout: col=lm -> node, row=4*quad+r -> b)
        #pragma unroll
        for (int m = 0; m < 2; ++m)
            #pragma unroll
            for (int nt = 0; nt < 4; ++nt)
                #pragma unroll
                for (int r = 0; r < 4; ++r)
                    sProbT[(32 * w + 16 * m + 4 * quad + r) * 72 + 16 * nt + lm + 1] =
                        (_Float16)sigmf(acc[m][nt][r]);
    }
    bar_lds();

    // ---- prefix probs sP0[sl][b] (fp16) ----
    {
        const int b = tid & 127, h2 = tid >> 7;
        const _Float16* pr = sProbT + b * 72;
        float pref = 1.f;
        #pragma unroll
        for (int d = 0; d < 6; ++d) {
            float pv = (float)pr[d + 1];
            pref *= ((g >> (5 - d)) & 1) ? (1.f - pv) : pv;
        }
        for (int sl = 8 * h2; sl < 8 * h2 + 8; ++sl) {
            const int a0 = sl >> 3, a1 = sl >> 2, a2 = sl >> 1;
            float P = pref, pv;
            pv = (float)pr[7];       P *= a0       ? (1.f - pv) : pv;
            pv = (float)pr[8 + a0];  P *= (a1 & 1) ? (1.f - pv) : pv;
            pv = (float)pr[10 + a1]; P *= (a2 & 1) ? (1.f - pv) : pv;
            pv = (float)pr[14 + a2]; P *= (sl & 1) ? (1.f - pv) : pv;
            sP0[sl * 132 + b] = (_Float16)P;
        }
    }
    bar_lds();

    // ---- output accumulators ----
    floatx4 O[2][4];
    #pragma unroll
    for (int m = 0; m < 2; ++m)
        #pragma unroll
        for (int nt = 0; nt < 4; ++nt) { O[m][nt][0]=0.f; O[m][nt][1]=0.f; O[m][nt][2]=0.f; O[m][nt][3]=0.f; }

    // ---- main loop: 16 subtrees of 64 leaves ----
    for (int sl = 0; sl < 16; ++sl) {
        const _Float16* rs = rec + (size_t)((g << 4) + sl) * 8192;

        // kdiff B-frags straight from global (L2-resident record)
        half8 kB[4][2];
        #pragma unroll
        for (int nt = 0; nt < 4; ++nt)
            #pragma unroll
            for (int kt = 0; kt < 2; ++kt)
                kB[nt][kt] = *(const half8*)(rs + (16 * nt + lm) * 64 + 32 * kt + 8 * quad);

        // GEMM1: logit diffs
        floatx4 acc[2][4];
        #pragma unroll
        for (int m = 0; m < 2; ++m)
            #pragma unroll
            for (int nt = 0; nt < 4; ++nt) { acc[m][nt][0]=0.f; acc[m][nt][1]=0.f; acc[m][nt][2]=0.f; acc[m][nt][3]=0.f; }
        #pragma unroll
        for (int nt = 0; nt < 4; ++nt)
            #pragma unroll
            for (int kt = 0; kt < 2; ++kt) {
                acc[0][nt] = mfma16(qA[0][kt], kB[nt][kt], acc[0][nt]);
                acc[1][nt] = mfma16(qA[1][kt], kB[nt][kt], acc[1][nt]);
            }

        // V^T B-frags (consumed at GEMM2; latency hidden across sigmoid+chain)
        half8 vB[4][2];
        #pragma unroll
        for (int nt = 0; nt < 4; ++nt)
            #pragma unroll
            for (int kt = 0; kt < 2; ++kt)
                vB[nt][kt] = *(const half8*)(rs + 4096 + (16 * nt + lm) * 64 + 32 * kt + 8 * quad);

        // sigmoid -> sProbT[b][node+1]
        #pragma unroll
        for (int m = 0; m < 2; ++m)
            #pragma unroll
            for (int nt = 0; nt < 4; ++nt)
                #pragma unroll
                for (int r = 0; r < 4; ++r)
                    sProbT[(32 * w + 16 * m + 4 * quad + r) * 72 + 16 * nt + lm + 1] =
                        (_Float16)sigmf(acc[m][nt][r]);
        bar_lds();

        // leaf probs: hierarchical product, vectorized transposed reads -> sA (swizzled)
        {
            const int b = tid & 127, h2 = tid >> 7;
            const _Float16* pr = sProbT + b * 72;
            const float P0v = (float)sP0[sl * 132 + b];
            half8 r0 = *(const half8*)(pr);   // cols 0..7 (col 0 unused)
            #pragma unroll
            for (int qi = 0; qi < 2; ++qi) {
                const int qq = 2 * h2 + qi;
                float p0 = (float)r0[1];
                float p1 = (float)r0[2 + (qq >> 1)];
                float P2 = P0v * (((qq >> 1) & 1) ? (1.f - p0) : p0)
                               * ((qq & 1) ? (1.f - p1) : p1);
                float p2 = (float)r0[4 + qq];
                float A3[2];
                A3[0] = P2 * p2; A3[1] = P2 * (1.f - p2);
                half2v r3 = *(const half2v*)(pr + 8 + 2 * qq);
                float A4[4];
                #pragma unroll
                for (int c = 0; c < 2; ++c) {
                    float pv = (float)r3[c];
                    A4[2 * c] = A3[c] * pv; A4[2 * c + 1] = A3[c] * (1.f - pv);
                }
                half4v r4 = *(const half4v*)(pr + 16 + 4 * qq);
                float A5[8];
                #pragma unroll
                for (int n = 0; n < 4; ++n) {
                    float pv = (float)r4[n];
                    A5[2 * n] = A4[n] * pv; A5[2 * n + 1] = A4[n] * (1.f - pv);
                }
                half8 r5 = *(const half8*)(pr + 32 + 8 * qq);
                half8 lo, hi;
                #pragma unroll
                for (int n = 0; n < 8; ++n) {
                    float pv = (float)r5[n];
                    float e0 = A5[n] * pv;
                    float e1 = A5[n] * (1.f - pv);
                    if (n < 4) { lo[2 * n] = (_Float16)e0; lo[2 * n + 1] = (_Float16)e1; }
                    else       { hi[2 * (n - 4)] = (_Float16)e0; hi[2 * (n - 4) + 1] = (_Float16)e1; }
                }
                *(half8*)(sA + b * 64 + (((2 * qq)     ^ (b & 7)) * 8)) = lo;
                *(half8*)(sA + b * 64 + (((2 * qq + 1) ^ (b & 7)) * 8)) = hi;
            }
        }
        bar_lds();

        // GEMM2: O += P(b,l) @ V(l,v)
        {
            half8 af[2][2];
            #pragma unroll
            for (int m = 0; m < 2; ++m)
                #pragma unroll
                for (int kt = 0; kt < 2; ++kt) {
                    const int row = 32 * w + 16 * m + lm;
                    af[m][kt] = *(const half8*)(sA + row * 64 + (((4 * kt + quad) ^ (row & 7)) * 8));
                }
            #pragma unroll
            for (int nt = 0; nt < 4; ++nt)
                #pragma unroll
                for (int kt = 0; kt < 2; ++kt) {
                    O[0][nt] = mfma16(af[0][kt], vB[nt][kt], O[0][nt]);
                    O[1][nt] = mfma16(af[1][kt], vB[nt][kt], O[1][nt]);
                }
        }
    }

    // ---- epilogue ----
    if (!use_atomic) {
        #pragma unroll
        for (int m = 0; m < 2; ++m)
            #pragma unroll
            for (int nt = 0; nt < 4; ++nt) {
                const int brow = tb * 128 + 32 * w + 16 * m + 4 * quad;
                const int v = 16 * nt + lm;
                const size_t base = ((size_t)g * 2048 + brow) * 64 + v;
                #pragma unroll
                for (int r = 0; r < 4; ++r)
                    outp[base + (size_t)r * 64] = O[m][nt][r];
            }
    } else {
        #pragma unroll
        for (int m = 0; m < 2; ++m)
            #pragma unroll
            for (int nt = 0; nt < 4; ++nt) {
                const int brow = tb * 128 + 32 * w + 16 * m + 4 * quad;
                const int v = 16 * nt + lm;
                #pragma unroll
                for (int r = 0; r < 4; ++r)
                    atomicAdd(&outp[(size_t)(brow + r) * 64 + v], O[m][nt][r]);
            }
    }
}

// out[b][v] = sum over 64 group partials
__global__ __launch_bounds__(256)
void tree_reduce(const float* __restrict__ part, float* __restrict__ outp)
{
    const int idx = blockIdx.x * 256 + threadIdx.x;  // 0..131071
    float s = 0.f;
    #pragma unroll 8
    for (int gg = 0; gg < 64; ++gg)
        s += part[(size_t)gg * 131072 + idx];
    outp[idx] = s;
}

extern "C" void kernel_launch(void* const* d_in, const int* in_sizes, int n_in,
                              void* d_out, int out_size, void* d_ws, size_t ws_size,
                              hipStream_t stream)
{
    const float* q  = (const float*)d_in[0];
    const float* tk = (const float*)d_in[1];
    const float* tv = (const float*)d_in[2];
    float* outp = (float*)d_out;

    _Float16* rec = (_Float16*)d_ws;
    const size_t REC_BYTES  = (size_t)1024 * 16384;                   // 16 MB records
    const size_t PART_BYTES = (size_t)64 * 2048 * 64 * sizeof(float); // 33.5 MB partials

    precompute<<<dim3(1024), dim3(256), 0, stream>>>(tk, tv, rec);

    if (ws_size >= REC_BYTES + PART_BYTES) {
        float* part = (float*)((char*)d_ws + REC_BYTES);
        tree_attn<<<dim3(1024), dim3(256), 0, stream>>>(q, tk, rec, part, 0);
        tree_reduce<<<dim3(512), dim3(256), 0, stream>>>(part, outp);
    } else {
        hipMemsetAsync(d_out, 0, (size_t)2048 * 64 * sizeof(float), stream);
        tree_attn<<<dim3(1024), dim3(256), 0, stream>>>(q, tk, rec, outp, 1);
    }
}

// Round 5
// 223.979 us; speedup vs baseline: 1.1213x; 1.1213x over previous
//
#include <hip/hip_runtime.h>
#include <stdint.h>

#define LOG2E 1.44269504088896f
#define PSTR  132   // sProb row stride in u32 pairs: 128 b-cols + 4 pad (16B-aligned rows)
#define P0STR 130   // sP0 row stride (h16), [sl][b]

typedef _Float16 half8  __attribute__((ext_vector_type(8)));
typedef _Float16 half2v __attribute__((ext_vector_type(2)));
typedef float    floatx4 __attribute__((ext_vector_type(4)));
typedef uint32_t uintx4  __attribute__((ext_vector_type(4)));

__device__ __forceinline__ floatx4 mfma16(half8 a, half8 b, floatx4 c) {
    return __builtin_amdgcn_mfma_f32_16x16x32_f16(a, b, c, 0, 0, 0);
}

__device__ __forceinline__ half2v bc(uint32_t v) {
    return __builtin_bit_cast(half2v, v);
}

// LDS-only barrier: waits lgkmcnt(0) but leaves vmcnt in flight.
// 0xC07F = vmcnt(63) expcnt(7) lgkmcnt(0).
#define bar_lds() do { __asm__ __volatile__("" ::: "memory"); \
    __builtin_amdgcn_s_waitcnt(0xC07F); \
    __builtin_amdgcn_s_barrier(); \
    __asm__ __volatile__("" ::: "memory"); } while (0)

// ---------------------------------------------------------------------------
// Precompute: per depth-10 subtree s (0..1023), a 16KB fp16 record:
//   [0,8192B)      kdiff rows j=0..62 (level order), row j = (K0-K1) * -LOG2E; row 63 = 0
//   [8192B,16384B) V^T rows v=0..63, col l = V[s*64+l][v]
// ---------------------------------------------------------------------------
__global__ __launch_bounds__(256, 4)
void precompute(const float* __restrict__ tkey, const float* __restrict__ tval,
                _Float16* __restrict__ rec)
{
    __shared__ _Float16 sVt[64 * 72];
    const int t = threadIdx.x;
    const int s = blockIdx.x;
    _Float16* r = rec + (size_t)s * 8192;

    {   // kdiff rows, scaled by -LOG2E
        const int j = t >> 2, part = t & 3;
        half8 h0, h1;
        if (j < 63) {
            const int u = j + 1;
            const int f = 31 - __builtin_clz((unsigned)u);
            const int i = u - (1 << f);
            const int gidx = ((1 << (10 + f)) - 1) + (s << f) + i;
            const floatx4* kp = (const floatx4*)(tkey + (size_t)gidx * 128);
            floatx4 a0 = kp[part * 4 + 0], a1 = kp[part * 4 + 1];
            floatx4 a2 = kp[part * 4 + 2], a3 = kp[part * 4 + 3];
            floatx4 b0 = kp[16 + part * 4 + 0], b1 = kp[16 + part * 4 + 1];
            floatx4 b2 = kp[16 + part * 4 + 2], b3 = kp[16 + part * 4 + 3];
            #pragma unroll
            for (int e = 0; e < 4; ++e) {
                h0[e]     = (_Float16)((a0[e] - b0[e]) * -LOG2E);
                h0[4 + e] = (_Float16)((a1[e] - b1[e]) * -LOG2E);
                h1[e]     = (_Float16)((a2[e] - b2[e]) * -LOG2E);
                h1[4 + e] = (_Float16)((a3[e] - b3[e]) * -LOG2E);
            }
        } else {
            #pragma unroll
            for (int e = 0; e < 8; ++e) { h0[e] = (_Float16)0.f; h1[e] = (_Float16)0.f; }
        }
        *(half8*)(r + j * 64 + part * 16)     = h0;
        *(half8*)(r + j * 64 + part * 16 + 8) = h1;
    }
    {   // V tile -> LDS fp16
        const int l = t >> 2, part = t & 3;
        const floatx4* vp = (const floatx4*)(tval + ((size_t)s * 64 + l) * 64);
        floatx4 f0 = vp[part * 4 + 0], f1 = vp[part * 4 + 1];
        floatx4 f2 = vp[part * 4 + 2], f3 = vp[part * 4 + 3];
        half8 h0, h1;
        #pragma unroll
        for (int e = 0; e < 4; ++e) {
            h0[e] = (_Float16)f0[e]; h0[4 + e] = (_Float16)f1[e];
            h1[e] = (_Float16)f2[e]; h1[4 + e] = (_Float16)f3[e];
        }
        *(half8*)(sVt + l * 72 + part * 16)     = h0;
        *(half8*)(sVt + l * 72 + part * 16 + 8) = h1;
    }
    __syncthreads();
    {   // V^T rows -> global
        const int v = t >> 2, p2 = t & 3;
        half8 hv0, hv1;
        #pragma unroll
        for (int e = 0; e < 8; ++e) {
            hv0[e] = sVt[(16 * p2 + e) * 72 + v];
            hv1[e] = sVt[(16 * p2 + 8 + e) * 72 + v];
        }
        *(half8*)(r + 4096 + v * 64 + p2 * 16)     = hv0;
        *(half8*)(r + 4096 + v * 64 + p2 * 16 + 8) = hv1;
    }
}

// ---------------------------------------------------------------------------
// Fused tree attention. blockIdx = tb*64 + g (same-g blocks -> same XCD L2).
// 128-row batch tiles (tb 0..15), g = depth-6 leaf group (0..63).
// ---------------------------------------------------------------------------
__global__ __launch_bounds__(256, 2)
void tree_attn(const float* __restrict__ q,
               const float* __restrict__ tkey,
               const _Float16* __restrict__ rec,
               float* __restrict__ outp,
               int use_atomic)
{
    __shared__ __align__(16) uint32_t sProb[64 * PSTR];  // (p,1-p) fp16 pairs, [node][b]
    __shared__ __align__(16) _Float16 sA[128 * 64];      // leaf probs, XOR-swizzled 16B chunks
    __shared__ __align__(16) _Float16 sP0[16 * P0STR];   // prefix probs [sl][b]

    const int tid  = threadIdx.x;
    const int w    = tid >> 6;
    const int lane = tid & 63;
    const int lm   = lane & 15;
    const int quad = lane >> 4;
    const int g    = blockIdx.x & 63;
    const int tb   = blockIdx.x >> 6;

    // ---- q A-fragments straight from global (fp32 -> fp16) ----
    half8 qA[2][2];
    #pragma unroll
    for (int m = 0; m < 2; ++m)
        #pragma unroll
        for (int kt = 0; kt < 2; ++kt) {
            const float* qp = q + (size_t)(tb * 128 + 32 * w + 16 * m + lm) * 64 + 32 * kt + 8 * quad;
            floatx4 f0 = *(const floatx4*)qp;
            floatx4 f1 = *(const floatx4*)(qp + 4);
            #pragma unroll
            for (int e = 0; e < 4; ++e) {
                qA[m][kt][e]     = (_Float16)f0[e];
                qA[m][kt][4 + e] = (_Float16)f1[e];
            }
        }

    // ---- prefix GEMM: 21 path/subtree nodes (depths 0..9), B on the fly ----
    {
        floatx4 pacc[2][2];
        #pragma unroll
        for (int m = 0; m < 2; ++m)
            #pragma unroll
            for (int nt = 0; nt < 2; ++nt) { pacc[m][nt][0]=0.f; pacc[m][nt][1]=0.f; pacc[m][nt][2]=0.f; pacc[m][nt][3]=0.f; }
        #pragma unroll
        for (int nt = 0; nt < 2; ++nt) {
            const int j = 16 * nt + lm;
            int gidx = 0;
            const bool valid = (j < 21);
            if (j < 6) gidx = (1 << j) - 1 + (g >> (6 - j));
            else if (j < 21) {
                const int u = j - 5;
                const int e = 31 - __builtin_clz((unsigned)u);
                const int i = u - (1 << e);
                gidx = ((1 << (6 + e)) - 1) + (g << e) + i;
            }
            #pragma unroll
            for (int kt = 0; kt < 2; ++kt) {
                half8 bf;
                if (valid) {
                    const float* kb = tkey + (size_t)gidx * 128 + 32 * kt + 8 * quad;
                    floatx4 f0 = *(const floatx4*)(kb);
                    floatx4 f1 = *(const floatx4*)(kb + 4);
                    floatx4 g0 = *(const floatx4*)(kb + 64);
                    floatx4 g1 = *(const floatx4*)(kb + 68);
                    #pragma unroll
                    for (int e = 0; e < 4; ++e) {
                        bf[e]     = (_Float16)((f0[e] - g0[e]) * -LOG2E);
                        bf[4 + e] = (_Float16)((f1[e] - g1[e]) * -LOG2E);
                    }
                } else {
                    #pragma unroll
                    for (int e = 0; e < 8; ++e) bf[e] = (_Float16)0.f;
                }
                pacc[0][nt] = mfma16(qA[0][kt], bf, pacc[0][nt]);
                pacc[1][nt] = mfma16(qA[1][kt], bf, pacc[1][nt]);
            }
        }
        // sigmoid -> (p,1-p) pairs -> sProb[node][b], vector b128 writes
        #pragma unroll
        for (int m = 0; m < 2; ++m)
            #pragma unroll
            for (int nt = 0; nt < 2; ++nt) {
                uintx4 pk;
                #pragma unroll
                for (int r = 0; r < 4; ++r) {
                    float e = __builtin_amdgcn_exp2f(pacc[m][nt][r]);
                    float p = __builtin_amdgcn_rcpf(1.0f + e);
                    pk[r] = __builtin_bit_cast(uint32_t, __builtin_amdgcn_cvt_pkrtz(p, e * p));
                }
                *(uintx4*)(sProb + (16 * nt + lm) * PSTR + 32 * w + 16 * m + 4 * quad) = pk;
            }
    }
    bar_lds();

    // ---- prefix probs sP0[sl][b] ----
    {
        const int b = tid & 127, slg = tid >> 7;
        const _Float16* prh = (const _Float16*)sProb;
        float pref = 1.f;
        #pragma unroll
        for (int d = 0; d < 6; ++d)
            pref *= (float)prh[(d * PSTR + b) * 2 + ((g >> (5 - d)) & 1)];
        for (int sl = 8 * slg; sl < 8 * slg + 8; ++sl) {
            const int a0 = sl >> 3, a1 = sl >> 2, a2 = sl >> 1;
            float P = pref;
            P *= (float)prh[(6 * PSTR + b) * 2 + a0];
            P *= (float)prh[((7 + a0) * PSTR + b) * 2 + (a1 & 1)];
            P *= (float)prh[((9 + a1) * PSTR + b) * 2 + (a2 & 1)];
            P *= (float)prh[((13 + a2) * PSTR + b) * 2 + (sl & 1)];
            sP0[sl * P0STR + b] = (_Float16)P;
        }
    }
    bar_lds();   // also guards sProb reuse by iter0 sigmoid

    // ---- output accumulators ----
    floatx4 O[2][4];
    #pragma unroll
    for (int m = 0; m < 2; ++m)
        #pragma unroll
        for (int nt = 0; nt < 4; ++nt) { O[m][nt][0]=0.f; O[m][nt][1]=0.f; O[m][nt][2]=0.f; O[m][nt][3]=0.f; }

    // ---- main loop: 16 subtrees of 64 leaves ----
    for (int sl = 0; sl < 16; ++sl) {
        const _Float16* rs = rec + (size_t)((g << 4) + sl) * 8192;

        // kdiff B-frags direct from global (L2-resident)
        half8 kB[4][2];
        #pragma unroll
        for (int nt = 0; nt < 4; ++nt)
            #pragma unroll
            for (int kt = 0; kt < 2; ++kt)
                kB[nt][kt] = *(const half8*)(rs + (16 * nt + lm) * 64 + 32 * kt + 8 * quad);

        // GEMM1: t = -logitdiff * log2e
        floatx4 acc[2][4];
        #pragma unroll
        for (int m = 0; m < 2; ++m)
            #pragma unroll
            for (int nt = 0; nt < 4; ++nt) { acc[m][nt][0]=0.f; acc[m][nt][1]=0.f; acc[m][nt][2]=0.f; acc[m][nt][3]=0.f; }
        #pragma unroll
        for (int nt = 0; nt < 4; ++nt)
            #pragma unroll
            for (int kt = 0; kt < 2; ++kt) {
                acc[0][nt] = mfma16(qA[0][kt], kB[nt][kt], acc[0][nt]);
                acc[1][nt] = mfma16(qA[1][kt], kB[nt][kt], acc[1][nt]);
            }

        // V^T B-frags (consumed at GEMM2; latency spans sigmoid+chain)
        half8 vB[4][2];
        #pragma unroll
        for (int nt = 0; nt < 4; ++nt)
            #pragma unroll
            for (int kt = 0; kt < 2; ++kt)
                vB[nt][kt] = *(const half8*)(rs + 4096 + (16 * nt + lm) * 64 + 32 * kt + 8 * quad);

        // sigmoid -> (p,1-p) pairs -> sProb[node][b], 8 b128 writes
        #pragma unroll
        for (int m = 0; m < 2; ++m)
            #pragma unroll
            for (int nt = 0; nt < 4; ++nt) {
                uintx4 pk;
                #pragma unroll
                for (int r = 0; r < 4; ++r) {
                    float e = __builtin_amdgcn_exp2f(acc[m][nt][r]);
                    float p = __builtin_amdgcn_rcpf(1.0f + e);
                    pk[r] = __builtin_bit_cast(uint32_t, __builtin_amdgcn_cvt_pkrtz(p, e * p));
                }
                *(uintx4*)(sProb + (16 * nt + lm) * PSTR + 32 * w + 16 * m + 4 * quad) = pk;
            }
        bar_lds();

        // leaf probs: pk_mul hierarchical expansion -> sA (swizzled)
        {
            const int b  = tid & 127;
            const int qh = tid >> 7;
            const float P0v = (float)sP0[sl * P0STR + b];
            const uint32_t* pr = sProb;
            const _Float16* prh = (const _Float16*)sProb;
            #pragma unroll
            for (int i = 0; i < 2; ++i) {
                const int qq = 2 * qh + i;
                float p0 = (float)prh[(0 * PSTR + b) * 2 + (qq >> 1)];
                float p1 = (float)prh[((1 + (qq >> 1)) * PSTR + b) * 2 + (qq & 1)];
                _Float16 P2 = (_Float16)(P0v * p0 * p1);
                half2v A3 = half2v{P2, P2} * bc(pr[(3 + qq) * PSTR + b]);
                half2v A4a = half2v{A3.x, A3.x} * bc(pr[(7 + 2 * qq) * PSTR + b]);
                half2v A4b = half2v{A3.y, A3.y} * bc(pr[(8 + 2 * qq) * PSTR + b]);
                half2v A5[4];
                A5[0] = half2v{A4a.x, A4a.x} * bc(pr[(15 + 4 * qq) * PSTR + b]);
                A5[1] = half2v{A4a.y, A4a.y} * bc(pr[(16 + 4 * qq) * PSTR + b]);
                A5[2] = half2v{A4b.x, A4b.x} * bc(pr[(17 + 4 * qq) * PSTR + b]);
                A5[3] = half2v{A4b.y, A4b.y} * bc(pr[(18 + 4 * qq) * PSTR + b]);
                half8 lo, hi;
                #pragma unroll
                for (int n = 0; n < 4; ++n) {
                    half2v La = half2v{A5[n].x, A5[n].x} * bc(pr[(31 + 8 * qq + 2 * n) * PSTR + b]);
                    half2v Lb = half2v{A5[n].y, A5[n].y} * bc(pr[(32 + 8 * qq + 2 * n) * PSTR + b]);
                    if (n < 2) { lo[4*n] = La.x; lo[4*n+1] = La.y; lo[4*n+2] = Lb.x; lo[4*n+3] = Lb.y; }
                    else { hi[4*(n-2)] = La.x; hi[4*(n-2)+1] = La.y; hi[4*(n-2)+2] = Lb.x; hi[4*(n-2)+3] = Lb.y; }
                }
                *(half8*)(sA + b * 64 + (((2 * qq)     ^ (b & 7)) << 3)) = lo;
                *(half8*)(sA + b * 64 + (((2 * qq + 1) ^ (b & 7)) << 3)) = hi;
            }
        }
        bar_lds();

        // GEMM2: O += P(b,l) @ V(l,v)
        {
            half8 af[2][2];
            #pragma unroll
            for (int m = 0; m < 2; ++m)
                #pragma unroll
                for (int kt = 0; kt < 2; ++kt) {
                    const int row = 32 * w + 16 * m + lm;
                    af[m][kt] = *(const half8*)(sA + row * 64 + (((4 * kt + quad) ^ (lm & 7)) << 3));
                }
            #pragma unroll
            for (int nt = 0; nt < 4; ++nt)
                #pragma unroll
                for (int kt = 0; kt < 2; ++kt) {
                    O[0][nt] = mfma16(af[0][kt], vB[nt][kt], O[0][nt]);
                    O[1][nt] = mfma16(af[1][kt], vB[nt][kt], O[1][nt]);
                }
        }
    }

    // ---- epilogue ----
    if (!use_atomic) {
        #pragma unroll
        for (int m = 0; m < 2; ++m)
            #pragma unroll
            for (int nt = 0; nt < 4; ++nt) {
                const int brow = tb * 128 + 32 * w + 16 * m + 4 * quad;
                const int v = 16 * nt + lm;
                const size_t base = ((size_t)g * 2048 + brow) * 64 + v;
                #pragma unroll
                for (int r = 0; r < 4; ++r)
                    outp[base + (size_t)r * 64] = O[m][nt][r];
            }
    } else {
        #pragma unroll
        for (int m = 0; m < 2; ++m)
            #pragma unroll
            for (int nt = 0; nt < 4; ++nt) {
                const int brow = tb * 128 + 32 * w + 16 * m + 4 * quad;
                const int v = 16 * nt + lm;
                #pragma unroll
                for (int r = 0; r < 4; ++r)
                    atomicAdd(&outp[(size_t)(brow + r) * 64 + v], O[m][nt][r]);
            }
    }
}

// out[b][v] = sum over 64 group partials
__global__ __launch_bounds__(256)
void tree_reduce(const float* __restrict__ part, float* __restrict__ outp)
{
    const int idx = blockIdx.x * 256 + threadIdx.x;  // 0..131071
    float s = 0.f;
    #pragma unroll 8
    for (int gg = 0; gg < 64; ++gg)
        s += part[(size_t)gg * 131072 + idx];
    outp[idx] = s;
}

extern "C" void kernel_launch(void* const* d_in, const int* in_sizes, int n_in,
                              void* d_out, int out_size, void* d_ws, size_t ws_size,
                              hipStream_t stream)
{
    const float* q  = (const float*)d_in[0];
    const float* tk = (const float*)d_in[1];
    const float* tv = (const float*)d_in[2];
    float* outp = (float*)d_out;

    _Float16* rec = (_Float16*)d_ws;
    const size_t REC_BYTES  = (size_t)1024 * 16384;
    const size_t PART_BYTES = (size_t)64 * 2048 * 64 * sizeof(float);

    precompute<<<dim3(1024), dim3(256), 0, stream>>>(tk, tv, rec);

    if (ws_size >= REC_BYTES + PART_BYTES) {
        float* part = (float*)((char*)d_ws + REC_BYTES);
        tree_attn<<<dim3(1024), dim3(256), 0, stream>>>(q, tk, rec, part, 0);
        tree_reduce<<<dim3(512), dim3(256), 0, stream>>>(part, outp);
    } else {
        hipMemsetAsync(d_out, 0, (size_t)2048 * 64 * sizeof(float), stream);
        tree_attn<<<dim3(1024), dim3(256), 0, stream>>>(q, tk, rec, outp, 1);
    }
}

// Round 6
// 222.947 us; speedup vs baseline: 1.1265x; 1.0046x over previous
//
#include <hip/hip_runtime.h>
#include <stdint.h>

#define LOG2E 1.44269504088896f
#define PSTR  132   // sProb row stride in u32 pairs: 128 b-cols + 4 pad (16B-aligned rows)
#define P0STR 130   // sP0 row stride (h16), [sl][b]

typedef _Float16 half8  __attribute__((ext_vector_type(8)));
typedef _Float16 half2v __attribute__((ext_vector_type(2)));
typedef float    floatx4 __attribute__((ext_vector_type(4)));
typedef uint32_t uintx4  __attribute__((ext_vector_type(4)));

__device__ __forceinline__ floatx4 mfma16(half8 a, half8 b, floatx4 c) {
    return __builtin_amdgcn_mfma_f32_16x16x32_f16(a, b, c, 0, 0, 0);
}

__device__ __forceinline__ half2v bc(uint32_t v) {
    return __builtin_bit_cast(half2v, v);
}

// Full-block LDS barrier (prologue only): waits lgkmcnt(0), leaves vmcnt in flight.
#define bar_lds() do { __asm__ __volatile__("" ::: "memory"); \
    __builtin_amdgcn_s_waitcnt(0xC07F); \
    __builtin_amdgcn_s_barrier(); \
    __asm__ __volatile__("" ::: "memory"); } while (0)

// Wave-local LDS drain (no barrier): all main-loop LDS traffic is wave-private.
#define wv_wait() do { __asm__ __volatile__("" ::: "memory"); \
    __builtin_amdgcn_s_waitcnt(0xC07F); \
    __asm__ __volatile__("" ::: "memory"); } while (0)

// ---------------------------------------------------------------------------
// Precompute: per depth-10 subtree s (0..1023), a 16KB fp16 record:
//   [0,8192B)      kdiff rows j=0..62 (level order), row j = (K0-K1) * -LOG2E; row 63 = 0
//   [8192B,16384B) V^T rows v=0..63, col l = V[s*64+l][v]
// ---------------------------------------------------------------------------
__global__ __launch_bounds__(256, 4)
void precompute(const float* __restrict__ tkey, const float* __restrict__ tval,
                _Float16* __restrict__ rec)
{
    __shared__ _Float16 sVt[64 * 72];
    const int t = threadIdx.x;
    const int s = blockIdx.x;
    _Float16* r = rec + (size_t)s * 8192;

    {   // kdiff rows, scaled by -LOG2E
        const int j = t >> 2, part = t & 3;
        half8 h0, h1;
        if (j < 63) {
            const int u = j + 1;
            const int f = 31 - __builtin_clz((unsigned)u);
            const int i = u - (1 << f);
            const int gidx = ((1 << (10 + f)) - 1) + (s << f) + i;
            const floatx4* kp = (const floatx4*)(tkey + (size_t)gidx * 128);
            floatx4 a0 = kp[part * 4 + 0], a1 = kp[part * 4 + 1];
            floatx4 a2 = kp[part * 4 + 2], a3 = kp[part * 4 + 3];
            floatx4 b0 = kp[16 + part * 4 + 0], b1 = kp[16 + part * 4 + 1];
            floatx4 b2 = kp[16 + part * 4 + 2], b3 = kp[16 + part * 4 + 3];
            #pragma unroll
            for (int e = 0; e < 4; ++e) {
                h0[e]     = (_Float16)((a0[e] - b0[e]) * -LOG2E);
                h0[4 + e] = (_Float16)((a1[e] - b1[e]) * -LOG2E);
                h1[e]     = (_Float16)((a2[e] - b2[e]) * -LOG2E);
                h1[4 + e] = (_Float16)((a3[e] - b3[e]) * -LOG2E);
            }
        } else {
            #pragma unroll
            for (int e = 0; e < 8; ++e) { h0[e] = (_Float16)0.f; h1[e] = (_Float16)0.f; }
        }
        *(half8*)(r + j * 64 + part * 16)     = h0;
        *(half8*)(r + j * 64 + part * 16 + 8) = h1;
    }
    {   // V tile -> LDS fp16
        const int l = t >> 2, part = t & 3;
        const floatx4* vp = (const floatx4*)(tval + ((size_t)s * 64 + l) * 64);
        floatx4 f0 = vp[part * 4 + 0], f1 = vp[part * 4 + 1];
        floatx4 f2 = vp[part * 4 + 2], f3 = vp[part * 4 + 3];
        half8 h0, h1;
        #pragma unroll
        for (int e = 0; e < 4; ++e) {
            h0[e] = (_Float16)f0[e]; h0[4 + e] = (_Float16)f1[e];
            h1[e] = (_Float16)f2[e]; h1[4 + e] = (_Float16)f3[e];
        }
        *(half8*)(sVt + l * 72 + part * 16)     = h0;
        *(half8*)(sVt + l * 72 + part * 16 + 8) = h1;
    }
    __syncthreads();
    {   // V^T rows -> global
        const int v = t >> 2, p2 = t & 3;
        half8 hv0, hv1;
        #pragma unroll
        for (int e = 0; e < 8; ++e) {
            hv0[e] = sVt[(16 * p2 + e) * 72 + v];
            hv1[e] = sVt[(16 * p2 + 8 + e) * 72 + v];
        }
        *(half8*)(r + 4096 + v * 64 + p2 * 16)     = hv0;
        *(half8*)(r + 4096 + v * 64 + p2 * 16 + 8) = hv1;
    }
}

// ---------------------------------------------------------------------------
// Fused tree attention. blockIdx = tb*64 + g (same-g blocks -> same XCD L2).
// Main loop is BARRIER-FREE: wave w owns batch rows [32w,32w+32) end to end
// (GEMM1 acc rows, sProb b-columns, chain, sA rows, GEMM2) -> all LDS
// producer/consumer edges are wave-internal; only wave-local lgkm waits.
// ---------------------------------------------------------------------------
__global__ __launch_bounds__(256, 2)
void tree_attn(const float* __restrict__ q,
               const float* __restrict__ tkey,
               const _Float16* __restrict__ rec,
               float* __restrict__ outp,
               int use_atomic)
{
    __shared__ __align__(16) uint32_t sProb[64 * PSTR];  // (p,1-p) fp16 pairs, [node][b]
    __shared__ __align__(16) _Float16 sA[128 * 64];      // leaf probs, XOR-swizzled 16B chunks
    __shared__ __align__(16) _Float16 sP0[16 * P0STR];   // prefix probs [sl][b]

    const int tid  = threadIdx.x;
    const int w    = tid >> 6;
    const int lane = tid & 63;
    const int lm   = lane & 15;
    const int quad = lane >> 4;
    const int g    = blockIdx.x & 63;
    const int tb   = blockIdx.x >> 6;

    // ---- q A-fragments straight from global (fp32 -> fp16) ----
    half8 qA[2][2];
    #pragma unroll
    for (int m = 0; m < 2; ++m)
        #pragma unroll
        for (int kt = 0; kt < 2; ++kt) {
            const float* qp = q + (size_t)(tb * 128 + 32 * w + 16 * m + lm) * 64 + 32 * kt + 8 * quad;
            floatx4 f0 = *(const floatx4*)qp;
            floatx4 f1 = *(const floatx4*)(qp + 4);
            #pragma unroll
            for (int e = 0; e < 4; ++e) {
                qA[m][kt][e]     = (_Float16)f0[e];
                qA[m][kt][4 + e] = (_Float16)f1[e];
            }
        }

    // ---- prefix GEMM: 21 path/subtree nodes (depths 0..9), B on the fly ----
    {
        floatx4 pacc[2][2];
        #pragma unroll
        for (int m = 0; m < 2; ++m)
            #pragma unroll
            for (int nt = 0; nt < 2; ++nt) { pacc[m][nt][0]=0.f; pacc[m][nt][1]=0.f; pacc[m][nt][2]=0.f; pacc[m][nt][3]=0.f; }
        #pragma unroll
        for (int nt = 0; nt < 2; ++nt) {
            const int j = 16 * nt + lm;
            int gidx = 0;
            const bool valid = (j < 21);
            if (j < 6) gidx = (1 << j) - 1 + (g >> (6 - j));
            else if (j < 21) {
                const int u = j - 5;
                const int e = 31 - __builtin_clz((unsigned)u);
                const int i = u - (1 << e);
                gidx = ((1 << (6 + e)) - 1) + (g << e) + i;
            }
            #pragma unroll
            for (int kt = 0; kt < 2; ++kt) {
                half8 bf;
                if (valid) {
                    const float* kb = tkey + (size_t)gidx * 128 + 32 * kt + 8 * quad;
                    floatx4 f0 = *(const floatx4*)(kb);
                    floatx4 f1 = *(const floatx4*)(kb + 4);
                    floatx4 g0 = *(const floatx4*)(kb + 64);
                    floatx4 g1 = *(const floatx4*)(kb + 68);
                    #pragma unroll
                    for (int e = 0; e < 4; ++e) {
                        bf[e]     = (_Float16)((f0[e] - g0[e]) * -LOG2E);
                        bf[4 + e] = (_Float16)((f1[e] - g1[e]) * -LOG2E);
                    }
                } else {
                    #pragma unroll
                    for (int e = 0; e < 8; ++e) bf[e] = (_Float16)0.f;
                }
                pacc[0][nt] = mfma16(qA[0][kt], bf, pacc[0][nt]);
                pacc[1][nt] = mfma16(qA[1][kt], bf, pacc[1][nt]);
            }
        }
        // sigmoid -> (p,1-p) pairs -> sProb[node][b], vector b128 writes
        #pragma unroll
        for (int m = 0; m < 2; ++m)
            #pragma unroll
            for (int nt = 0; nt < 2; ++nt) {
                uintx4 pk;
                #pragma unroll
                for (int r = 0; r < 4; ++r) {
                    float e = __builtin_amdgcn_exp2f(pacc[m][nt][r]);
                    float p = __builtin_amdgcn_rcpf(1.0f + e);
                    pk[r] = __builtin_bit_cast(uint32_t, __builtin_amdgcn_cvt_pkrtz(p, e * p));
                }
                *(uintx4*)(sProb + (16 * nt + lm) * PSTR + 32 * w + 16 * m + 4 * quad) = pk;
            }
    }
    bar_lds();

    // ---- prefix probs sP0[sl][b] (cross-wave; barriered) ----
    {
        const int b = tid & 127, slg = tid >> 7;
        const _Float16* prh = (const _Float16*)sProb;
        float pref = 1.f;
        #pragma unroll
        for (int d = 0; d < 6; ++d)
            pref *= (float)prh[(d * PSTR + b) * 2 + ((g >> (5 - d)) & 1)];
        for (int sl = 8 * slg; sl < 8 * slg + 8; ++sl) {
            const int a0 = sl >> 3, a1 = sl >> 2, a2 = sl >> 1;
            float P = pref;
            P *= (float)prh[(6 * PSTR + b) * 2 + a0];
            P *= (float)prh[((7 + a0) * PSTR + b) * 2 + (a1 & 1)];
            P *= (float)prh[((9 + a1) * PSTR + b) * 2 + (a2 & 1)];
            P *= (float)prh[((13 + a2) * PSTR + b) * 2 + (sl & 1)];
            sP0[sl * P0STR + b] = (_Float16)P;
        }
    }
    bar_lds();   // guards sProb WAR (iter0 sigmoid) + sP0 visibility

    // ---- output accumulators ----
    floatx4 O[2][4];
    #pragma unroll
    for (int m = 0; m < 2; ++m)
        #pragma unroll
        for (int nt = 0; nt < 4; ++nt) { O[m][nt][0]=0.f; O[m][nt][1]=0.f; O[m][nt][2]=0.f; O[m][nt][3]=0.f; }

    // ---- main loop: 16 subtrees of 64 leaves; NO barriers ----
    for (int sl = 0; sl < 16; ++sl) {
        const _Float16* rs = rec + (size_t)((g << 4) + sl) * 8192;

        // kdiff B-frags direct from global (L2-resident)
        half8 kB[4][2];
        #pragma unroll
        for (int nt = 0; nt < 4; ++nt)
            #pragma unroll
            for (int kt = 0; kt < 2; ++kt)
                kB[nt][kt] = *(const half8*)(rs + (16 * nt + lm) * 64 + 32 * kt + 8 * quad);

        // GEMM1: t = -logitdiff * log2e
        floatx4 acc[2][4];
        #pragma unroll
        for (int m = 0; m < 2; ++m)
            #pragma unroll
            for (int nt = 0; nt < 4; ++nt) { acc[m][nt][0]=0.f; acc[m][nt][1]=0.f; acc[m][nt][2]=0.f; acc[m][nt][3]=0.f; }
        #pragma unroll
        for (int nt = 0; nt < 4; ++nt)
            #pragma unroll
            for (int kt = 0; kt < 2; ++kt) {
                acc[0][nt] = mfma16(qA[0][kt], kB[nt][kt], acc[0][nt]);
                acc[1][nt] = mfma16(qA[1][kt], kB[nt][kt], acc[1][nt]);
            }

        // V^T B-frags (consumed at GEMM2; latency spans sigmoid+chain)
        half8 vB[4][2];
        #pragma unroll
        for (int nt = 0; nt < 4; ++nt)
            #pragma unroll
            for (int kt = 0; kt < 2; ++kt)
                vB[nt][kt] = *(const half8*)(rs + 4096 + (16 * nt + lm) * 64 + 32 * kt + 8 * quad);

        // sigmoid -> (p,1-p) pairs -> sProb[node][32w..32w+32)  (wave-private cols)
        #pragma unroll
        for (int m = 0; m < 2; ++m)
            #pragma unroll
            for (int nt = 0; nt < 4; ++nt) {
                uintx4 pk;
                #pragma unroll
                for (int r = 0; r < 4; ++r) {
                    float e = __builtin_amdgcn_exp2f(acc[m][nt][r]);
                    float p = __builtin_amdgcn_rcpf(1.0f + e);
                    pk[r] = __builtin_bit_cast(uint32_t, __builtin_amdgcn_cvt_pkrtz(p, e * p));
                }
                *(uintx4*)(sProb + (16 * nt + lm) * PSTR + 32 * w + 16 * m + 4 * quad) = pk;
            }
        wv_wait();   // own writes visible to own reads

        // leaf probs: chain reads own wave's b-columns, writes own sA rows
        {
            const int b  = 32 * w + (lane & 31);
            const int qh = lane >> 5;
            const float P0v = (float)sP0[sl * P0STR + b];
            const uint32_t* pr = sProb;
            const _Float16* prh = (const _Float16*)sProb;
            #pragma unroll
            for (int i = 0; i < 2; ++i) {
                const int qq = 2 * qh + i;
                float p0 = (float)prh[(0 * PSTR + b) * 2 + (qq >> 1)];
                float p1 = (float)prh[((1 + (qq >> 1)) * PSTR + b) * 2 + (qq & 1)];
                _Float16 P2 = (_Float16)(P0v * p0 * p1);
                half2v A3 = half2v{P2, P2} * bc(pr[(3 + qq) * PSTR + b]);
                half2v A4a = half2v{A3.x, A3.x} * bc(pr[(7 + 2 * qq) * PSTR + b]);
                half2v A4b = half2v{A3.y, A3.y} * bc(pr[(8 + 2 * qq) * PSTR + b]);
                half2v A5[4];
                A5[0] = half2v{A4a.x, A4a.x} * bc(pr[(15 + 4 * qq) * PSTR + b]);
                A5[1] = half2v{A4a.y, A4a.y} * bc(pr[(16 + 4 * qq) * PSTR + b]);
                A5[2] = half2v{A4b.x, A4b.x} * bc(pr[(17 + 4 * qq) * PSTR + b]);
                A5[3] = half2v{A4b.y, A4b.y} * bc(pr[(18 + 4 * qq) * PSTR + b]);
                half8 lo, hi;
                #pragma unroll
                for (int n = 0; n < 4; ++n) {
                    half2v La = half2v{A5[n].x, A5[n].x} * bc(pr[(31 + 8 * qq + 2 * n) * PSTR + b]);
                    half2v Lb = half2v{A5[n].y, A5[n].y} * bc(pr[(32 + 8 * qq + 2 * n) * PSTR + b]);
                    if (n < 2) { lo[4*n] = La.x; lo[4*n+1] = La.y; lo[4*n+2] = Lb.x; lo[4*n+3] = Lb.y; }
                    else { hi[4*(n-2)] = La.x; hi[4*(n-2)+1] = La.y; hi[4*(n-2)+2] = Lb.x; hi[4*(n-2)+3] = Lb.y; }
                }
                *(half8*)(sA + b * 64 + (((2 * qq)     ^ (b & 7)) << 3)) = lo;
                *(half8*)(sA + b * 64 + (((2 * qq + 1) ^ (b & 7)) << 3)) = hi;
            }
        }
        wv_wait();   // own sA writes visible to own af reads

        // GEMM2: O += P(b,l) @ V(l,v)  (rows 32w..32w+32 only)
        {
            half8 af[2][2];
            #pragma unroll
            for (int m = 0; m < 2; ++m)
                #pragma unroll
                for (int kt = 0; kt < 2; ++kt) {
                    const int row = 32 * w + 16 * m + lm;
                    af[m][kt] = *(const half8*)(sA + row * 64 + (((4 * kt + quad) ^ (lm & 7)) << 3));
                }
            #pragma unroll
            for (int nt = 0; nt < 4; ++nt)
                #pragma unroll
                for (int kt = 0; kt < 2; ++kt) {
                    O[0][nt] = mfma16(af[0][kt], vB[nt][kt], O[0][nt]);
                    O[1][nt] = mfma16(af[1][kt], vB[nt][kt], O[1][nt]);
                }
        }
    }

    // ---- epilogue ----
    if (!use_atomic) {
        #pragma unroll
        for (int m = 0; m < 2; ++m)
            #pragma unroll
            for (int nt = 0; nt < 4; ++nt) {
                const int brow = tb * 128 + 32 * w + 16 * m + 4 * quad;
                const int v = 16 * nt + lm;
                const size_t base = ((size_t)g * 2048 + brow) * 64 + v;
                #pragma unroll
                for (int r = 0; r < 4; ++r)
                    outp[base + (size_t)r * 64] = O[m][nt][r];
            }
    } else {
        #pragma unroll
        for (int m = 0; m < 2; ++m)
            #pragma unroll
            for (int nt = 0; nt < 4; ++nt) {
                const int brow = tb * 128 + 32 * w + 16 * m + 4 * quad;
                const int v = 16 * nt + lm;
                #pragma unroll
                for (int r = 0; r < 4; ++r)
                    atomicAdd(&outp[(size_t)(brow + r) * 64 + v], O[m][nt][r]);
            }
    }
}

// out[b][v] = sum over 64 group partials
__global__ __launch_bounds__(256)
void tree_reduce(const float* __restrict__ part, float* __restrict__ outp)
{
    const int idx = blockIdx.x * 256 + threadIdx.x;  // 0..131071
    float s = 0.f;
    #pragma unroll 8
    for (int gg = 0; gg < 64; ++gg)
        s += part[(size_t)gg * 131072 + idx];
    outp[idx] = s;
}

extern "C" void kernel_launch(void* const* d_in, const int* in_sizes, int n_in,
                              void* d_out, int out_size, void* d_ws, size_t ws_size,
                              hipStream_t stream)
{
    const float* q  = (const float*)d_in[0];
    const float* tk = (const float*)d_in[1];
    const float* tv = (const float*)d_in[2];
    float* outp = (float*)d_out;

    _Float16* rec = (_Float16*)d_ws;
    const size_t REC_BYTES  = (size_t)1024 * 16384;
    const size_t PART_BYTES = (size_t)64 * 2048 * 64 * sizeof(float);

    precompute<<<dim3(1024), dim3(256), 0, stream>>>(tk, tv, rec);

    if (ws_size >= REC_BYTES + PART_BYTES) {
        float* part = (float*)((char*)d_ws + REC_BYTES);
        tree_attn<<<dim3(1024), dim3(256), 0, stream>>>(q, tk, rec, part, 0);
        tree_reduce<<<dim3(512), dim3(256), 0, stream>>>(part, outp);
    } else {
        hipMemsetAsync(d_out, 0, (size_t)2048 * 64 * sizeof(float), stream);
        tree_attn<<<dim3(1024), dim3(256), 0, stream>>>(q, tk, rec, outp, 1);
    }
}